// Round 7
// baseline (467.944 us; speedup 1.0000x reference)
//
#include <hip/hip_runtime.h>

typedef _Float16 f16;
typedef _Float16 f16x4 __attribute__((ext_vector_type(4)));
typedef _Float16 f16x8 __attribute__((ext_vector_type(8)));
typedef float    f32x4 __attribute__((ext_vector_type(4)));

#define SEQ   1024
#define HID   512
#define NHEAD 8
#define DH    256
#define INTER 2048
#define BATCH 8
#define ROWS  (BATCH * SEQ)   // 8192

// async global->LDS, 16B per lane. LDS dest is wave-uniform base + lane*16.
__device__ __forceinline__ void g2l16(const void* g, void* l) {
  __builtin_amdgcn_global_load_lds(
      (const __attribute__((address_space(1))) void*)g,
      (__attribute__((address_space(3))) void*)l, 16, 0, 0);
}

// ===========================================================================
// 256x256 wave-private core: 4 waves (2Mx2N), per-wave 128x128 output,
// BK=32, ring-2 private LDS, ZERO barriers in the K-loop.
// C(256x256) += A(256xK) * B^T(256xK); operands k-fast row-major, ld == K.
// Each wave stages ITS OWN 128-row A-panel and 128-row B-panel into its own
// 2x16KiB LDS region (A,B subtiles of 8KiB each) and waits only on its own
// vmcnt -> waves free-run; one SIMD's LDS burst overlaps another's MFMA.
// Ring-2 ordering is per-wave program order: stage(t+2) into slot t&1 is
// issued AFTER the lgkm-drained MFMAs that consumed slot t's reads (A-stage
// after column 0 - all a[] consumed; B-stage after column 7 - b[7] consumed);
// reads(t+1) target the other slot; vmcnt(16) at iter end leaves only
// tile t+2's 16 calls in flight => tile t+1 resident (oldest-first count).
// Swizzle (verified 0-conflict): k-octet q of row r at slot q^((r>>1)&3),
// involution pre-applied on the GLOBAL source; ds_read applies the same.
// Staging lane map: call j, lane l -> row j*16+(l>>2), slot l&3, global
// octet (l&3)^(((l>>2)>>1)&3) == slot^((row>>1)&3)  (consistent).
// ===========================================================================
__device__ __forceinline__ void mm_core256w(const f16* __restrict__ At,
                                            const f16* __restrict__ Bt,
                                            int K, f32x4 (&acc)[8][8]) {
  __shared__ __align__(16) f16 L[4][2][8192];   // [wave][slot][A:0..4095|B:4096..8191]
  const int tid  = threadIdx.x;
  const int lane = tid & 63, wv = tid >> 6;
  const int wr = (wv >> 1) * 128, wc = (wv & 1) * 128;

  // staging geometry (per wave): subtile = 128 rows x 4 k-octets,
  // call j covers rows j*16 + (lane>>2), octet-slot lane&3.
  const int srow = lane >> 2, soct = lane & 3;
  const int swz  = soct ^ ((srow >> 1) & 3);           // global octet
  const f16* pA = At + (size_t)(wr + srow) * K + (swz << 3);
  const f16* pB = Bt + (size_t)(wc + srow) * K + (swz << 3);
  const size_t sK16 = (size_t)16 * K;                  // per-call row stride

  // fragment read offsets (within wave region; swizzled to match staging)
  int aoff[8], boff[8];
  const int lrow = lane & 15, q = lane >> 4;
  #pragma unroll
  for (int m = 0; m < 8; ++m) {
    int r = m * 16 + lrow;
    aoff[m] = r * 32 + ((q ^ ((r >> 1) & 3)) << 3);
    boff[m] = 4096 + aoff[m];      // same local-row formula for B region
  }

  f16* const W0 = &L[wv][0][0];
  f16* const W1 = &L[wv][1][0];

  const int nt = K >> 5;   // K-32 subtiles (nt >= 16 for all call sites)
  // prologue: stage tiles 0,1 into slots 0,1 (16 calls each)
  #pragma unroll
  for (int j = 0; j < 8; ++j) {
    g2l16(pA + j * sK16,      W0 + j * 512);
    g2l16(pB + j * sK16,      W0 + 4096 + j * 512);
  }
  #pragma unroll
  for (int j = 0; j < 8; ++j) {
    g2l16(pA + 32 + j * sK16, W1 + j * 512);
    g2l16(pB + 32 + j * sK16, W1 + 4096 + j * 512);
  }
  asm volatile("s_waitcnt vmcnt(16)" ::: "memory");   // tile 0 landed

  for (int t = 0; t < nt; ++t) {
    f16* const Wc = (t & 1) ? W1 : W0;
    const bool pf = (t + 2) < nt;
    const int kb = (t + 2) << 5;

    // read all A-frags + first B-frag
    f16x8 a[8];
    #pragma unroll
    for (int m = 0; m < 8; ++m) a[m] = *(const f16x8*)&Wc[aoff[m]];
    f16x8 b0 = *(const f16x8*)&Wc[boff[0]];

    // column 0 (consumes every a[m] -> all A reads of this slot drained)
    #pragma unroll
    for (int m = 0; m < 8; ++m)
      acc[m][0] = __builtin_amdgcn_mfma_f32_16x16x32_f16(a[m], b0,
                                                         acc[m][0], 0, 0, 0);
    // A-stage of tile t+2 into this slot's A region (safe: A reads done;
    // remaining columns read only the B region)
    if (pf) {
      #pragma unroll
      for (int j = 0; j < 8; ++j) g2l16(pA + kb + j * sK16, Wc + j * 512);
    }
    // columns 1..7
    #pragma unroll
    for (int n = 1; n < 8; ++n) {
      f16x8 bn = *(const f16x8*)&Wc[boff[n]];
      #pragma unroll
      for (int m = 0; m < 8; ++m)
        acc[m][n] = __builtin_amdgcn_mfma_f32_16x16x32_f16(a[m], bn,
                                                           acc[m][n], 0, 0, 0);
    }
    // B-stage of tile t+2 (safe: b[7] consumed above -> lgkm drained)
    if (pf) {
      #pragma unroll
      for (int j = 0; j < 8; ++j) g2l16(pB + kb + j * sK16, Wc + 4096 + j * 512);
      asm volatile("s_waitcnt vmcnt(16)" ::: "memory");  // t+1 resident
    } else if (t + 1 < nt) {
      asm volatile("s_waitcnt vmcnt(0)" ::: "memory");   // drain tail
    }
  }
}

__device__ __forceinline__ void zero_acc88(f32x4 (&acc)[8][8]) {
  f32x4 z = {0.f, 0.f, 0.f, 0.f};
  #pragma unroll
  for (int i = 0; i < 8; ++i)
    #pragma unroll
    for (int j = 0; j < 8; ++j) acc[i][j] = z;
}

// ---------------------------------------------------------------------------
// 256-tile GEMM writing activation in per-head transposed layout Xt[b,h,d,s].
// A: [8192][K] f16, W: [2048][K] f16. N fixed = 2048 (8 heads x 256).
// ---------------------------------------------------------------------------
__global__ __launch_bounds__(256, 1) void gemm256_t_kernel(
    const f16* __restrict__ A, const f16* __restrict__ W,
    f16* __restrict__ Xt, int K) {
  int row0 = blockIdx.y * 256, col0 = blockIdx.x * 256;
  f32x4 acc[8][8];
  zero_acc88(acc);
  mm_core256w(A + (size_t)row0 * K, W + (size_t)col0 * K, K, acc);
  int tid = threadIdx.x, lane = tid & 63, wv = tid >> 6;
  int wr = (wv >> 1) * 128, wc = (wv & 1) * 128;
  int cn = lane & 15, rbase = (lane >> 4) * 4;
  int b = row0 >> 10, sbase = row0 & 1023;
  #pragma unroll
  for (int m = 0; m < 8; ++m) {
    int s = sbase + wr + m * 16 + rbase;             // 4 consecutive s
    #pragma unroll
    for (int n = 0; n < 8; ++n) {
      int col = col0 + wc + n * 16 + cn;
      int h = col >> 8, d = col & 255;
      f16x4 v = {(f16)acc[m][n][0], (f16)acc[m][n][1],
                 (f16)acc[m][n][2], (f16)acc[m][n][3]};
      *(f16x4*)&Xt[(((size_t)(b * 8 + h) * 256 + d) << 10) + s] = v;
    }
  }
}

// ---------------------------------------------------------------------------
// 256-tile per-head seq mix + bias + square:
// Y[(b,t),(h,d)] = ( sum_s Mt[h,t,s] * Xt[b,h,d,s] + bias[h,d] )^2 (f16 out)
// grid: (1, SEQ/256, B*H). N-tile covers the full 256-d head.
// ---------------------------------------------------------------------------
__global__ __launch_bounds__(256, 1) void mut256_kernel(
    const f16* __restrict__ Mt, const f16* __restrict__ Xt,
    const float* __restrict__ bias, f16* __restrict__ Y) {
  int b = blockIdx.z >> 3, h = blockIdx.z & 7;
  int t0 = blockIdx.y * 256;
  f32x4 acc[8][8];
  zero_acc88(acc);
  const f16* Ap = Mt + ((size_t)h << 20) + ((size_t)t0 << 10);
  const f16* Bp = Xt + (((size_t)(b * 8 + h)) << 18);
  mm_core256w(Ap, Bp, SEQ, acc);
  int tid = threadIdx.x, lane = tid & 63, wv = tid >> 6;
  int wr = (wv >> 1) * 128, wc = (wv & 1) * 128;
  int cn = lane & 15, rbase = (lane >> 4) * 4;
  #pragma unroll
  for (int m = 0; m < 8; ++m) {
    int t = t0 + wr + m * 16 + rbase;
    #pragma unroll
    for (int n = 0; n < 8; ++n) {
      int d = wc + n * 16 + cn;
      float bb = bias[(h << 8) + d];
      size_t base = (((size_t)(b << 10) + t) << 11) + (h << 8) + d;
      #pragma unroll
      for (int r = 0; r < 4; ++r) {
        float v = acc[m][n][r] + bb;
        Y[base + (size_t)r * INTER] = (f16)(v * v);
      }
    }
  }
}

// ===========================================================================
// 128x128 core (verified): BK=32, global_load_lds staging, double buffer.
// Kept for gemm3 (N=512 -> 256-tile grid would underfill the GPU).
// ===========================================================================
__device__ __forceinline__ void mm_core(const f16* __restrict__ At,
                                        const f16* __restrict__ Bt,
                                        int K, f32x4 (&acc)[4][4]) {
  __shared__ __align__(16) f16 As[2 * 4096];
  __shared__ __align__(16) f16 Bs[2 * 4096];
  const int tid  = threadIdx.x;
  const int lane = tid & 63, wv = tid >> 6;
  const int wm = (wv >> 1) * 64, wn = (wv & 1) * 64;
  const int lrow  = lane & 15;
  const int kfrag = (lane >> 4) * 8;
  const int c0  = wv * 128 + lane;
  const int r0c = c0 >> 2, q0c = c0 & 3;
  const int c1  = c0 + 64;
  const int r1c = c1 >> 2, q1c = c1 & 3;
  const int ga0 = r0c * K + ((q0c ^ ((r0c >> 1) & 3)) << 3);
  const int ga1 = r1c * K + ((q1c ^ ((r1c >> 1) & 3)) << 3);
  f16* lA0 = &As[wv * 1024];
  f16* lA1 = &As[wv * 1024 + 512];
  f16* lB0 = &Bs[wv * 1024];
  f16* lB1 = &Bs[wv * 1024 + 512];
  int aoff[4], boff[4];
  #pragma unroll
  for (int t = 0; t < 4; ++t) {
    int ra = wm + t * 16 + lrow;
    aoff[t] = ra * 32 + (kfrag ^ (((ra >> 1) & 3) << 3));
    int rb = wn + t * 16 + lrow;
    boff[t] = rb * 32 + (kfrag ^ (((rb >> 1) & 3) << 3));
  }
  g2l16(At + ga0, lA0);
  g2l16(At + ga1, lA1);
  g2l16(Bt + ga0, lB0);
  g2l16(Bt + ga1, lB1);
  __syncthreads();
  int cur = 0;
  for (int k0 = 0; k0 < K; k0 += 32) {
    if (k0 + 32 < K) {
      const int nb = (cur ^ 1) * 4096;
      g2l16(At + (k0 + 32) + ga0, lA0 + nb);
      g2l16(At + (k0 + 32) + ga1, lA1 + nb);
      g2l16(Bt + (k0 + 32) + ga0, lB0 + nb);
      g2l16(Bt + (k0 + 32) + ga1, lB1 + nb);
    }
    const int cb = cur * 4096;
    f16x8 af[4], bf[4];
    #pragma unroll
    for (int t = 0; t < 4; ++t) {
      af[t] = *(const f16x8*)&As[cb + aoff[t]];
      bf[t] = *(const f16x8*)&Bs[cb + boff[t]];
    }
    #pragma unroll
    for (int i = 0; i < 4; ++i)
      #pragma unroll
      for (int j = 0; j < 4; ++j)
        acc[i][j] = __builtin_amdgcn_mfma_f32_16x16x32_f16(af[i], bf[j],
                                                           acc[i][j], 0, 0, 0);
    __syncthreads();
    cur ^= 1;
  }
}

__device__ __forceinline__ void zero_acc(f32x4 (&acc)[4][4]) {
  f32x4 z = {0.f, 0.f, 0.f, 0.f};
  #pragma unroll
  for (int i = 0; i < 4; ++i)
    #pragma unroll
    for (int j = 0; j < 4; ++j) acc[i][j] = z;
}

// ---------------------------------------------------------------------------
// final GEMM: out fp32 = A @ W^T + bias.  A: [8192][K] f16, W: [N][K] f16.
// ---------------------------------------------------------------------------
__global__ __launch_bounds__(256) void gemm_out_kernel(
    const f16* __restrict__ A, const f16* __restrict__ W,
    const float* __restrict__ bias, float* __restrict__ out, int K, int N) {
  int row0 = blockIdx.y * 128, col0 = blockIdx.x * 128;
  f32x4 acc[4][4];
  zero_acc(acc);
  mm_core(A + (size_t)row0 * K, W + (size_t)col0 * K, K, acc);
  int tid = threadIdx.x, lane = tid & 63, wv = tid >> 6;
  int wm = (wv >> 1) * 64, wn = (wv & 1) * 64;
  int cn = lane & 15, rbase = (lane >> 4) * 4;
  #pragma unroll
  for (int mt = 0; mt < 4; ++mt) {
    int r0 = row0 + wm + mt * 16 + rbase;
    #pragma unroll
    for (int nt = 0; nt < 4; ++nt) {
      int col = col0 + wn + nt * 16 + cn;
      float bb = bias[col];
      #pragma unroll
      for (int r = 0; r < 4; ++r)
        out[(size_t)(r0 + r) * N + col] = acc[mt][nt][r] + bb;
    }
  }
}

// ---------------------------------------------------------------------------
// embeddings + layernorm -> f16
// ---------------------------------------------------------------------------
__global__ __launch_bounds__(256) void embed_ln_kernel(
    const int* __restrict__ x, const float* __restrict__ wemb,
    const float* __restrict__ pemb, const float* __restrict__ temb,
    const float* __restrict__ lnw, const float* __restrict__ lnb,
    f16* __restrict__ out) {
  int row = blockIdx.x;
  int s = row & (SEQ - 1);
  int tok = x[row];
  const float* we = wemb + (size_t)tok * HID;
  const float* pe = pemb + (size_t)s * HID;
  int c = threadIdx.x;
  float e0 = we[c] + pe[c] + temb[c];
  float e1 = we[c + 256] + pe[c + 256] + temb[c + 256];
  float s1 = e0 + e1, s2 = e0 * e0 + e1 * e1;
  #pragma unroll
  for (int off = 32; off > 0; off >>= 1) {
    s1 += __shfl_down(s1, off, 64);
    s2 += __shfl_down(s2, off, 64);
  }
  __shared__ float r1[4], r2[4];
  int wid = threadIdx.x >> 6, lane = threadIdx.x & 63;
  if (lane == 0) { r1[wid] = s1; r2[wid] = s2; }
  __syncthreads();
  float S1 = r1[0] + r1[1] + r1[2] + r1[3];
  float S2 = r2[0] + r2[1] + r2[2] + r2[3];
  float m = S1 * (1.0f / HID);
  float v = S2 * (1.0f / HID) - m * m;
  float inv = rsqrtf(v + 1e-12f);
  f16* o = out + (size_t)row * HID;
  o[c]       = (f16)((e0 - m) * inv * lnw[c]       + lnb[c]);
  o[c + 256] = (f16)((e1 - m) * inv * lnw[c + 256] + lnb[c + 256]);
}

// ---------------------------------------------------------------------------
// f32 -> f16 cast (n % 4 == 0)
// ---------------------------------------------------------------------------
__global__ __launch_bounds__(256) void cast_f16_kernel(
    const float* __restrict__ in, f16* __restrict__ out, int n) {
  int i = (blockIdx.x * 256 + threadIdx.x) * 4;
  if (i < n) {
    float4 v = *(const float4*)(in + i);
    f16x4 o = {(f16)v.x, (f16)v.y, (f16)v.z, (f16)v.w};
    *(f16x4*)(out + i) = o;
  }
}

// ---------------------------------------------------------------------------
// per-head transpose+cast: Mt[h][t][s] = (f16) M[h][s][t]   (1024x1024 x 8)
// ---------------------------------------------------------------------------
__global__ __launch_bounds__(256) void mtrans_kernel(
    const float* __restrict__ M, f16* __restrict__ Mt) {
  __shared__ float T[32][33];
  int h = blockIdx.z;
  int s0 = blockIdx.y * 32, t0 = blockIdx.x * 32;
  int tx = threadIdx.x & 31, ty = threadIdx.x >> 5;   // ty 0..7
  const float* Mh = M + ((size_t)h << 20);
  #pragma unroll
  for (int i = 0; i < 32; i += 8)
    T[ty + i][tx] = Mh[((size_t)(s0 + ty + i) << 10) + t0 + tx];
  __syncthreads();
  f16* Mth = Mt + ((size_t)h << 20);
  #pragma unroll
  for (int i = 0; i < 32; i += 8)
    Mth[((size_t)(t0 + ty + i) << 10) + s0 + tx] = (f16)T[tx][ty + i];
}

// ---------------------------------------------------------------------------
extern "C" void kernel_launch(void* const* d_in, const int* in_sizes, int n_in,
                              void* d_out, int out_size, void* d_ws, size_t ws_size,
                              hipStream_t stream) {
  const int*   x        = (const int*)d_in[0];
  const float* wemb     = (const float*)d_in[1];
  const float* pemb     = (const float*)d_in[2];
  const float* temb     = (const float*)d_in[3];
  const float* lnw      = (const float*)d_in[4];
  const float* lnb      = (const float*)d_in[5];
  const float* init_d   = (const float*)d_in[6];
  const float* init_b   = (const float*)d_in[7];
  const float* init_M   = (const float*)d_in[8];
  const float* inter0_d = (const float*)d_in[9];
  const float* inter0_b = (const float*)d_in[10];
  const float* inter0_M = (const float*)d_in[11];
  const float* final_d  = (const float*)d_in[12];
  const float* final_b  = (const float*)d_in[13];
  float* out = (float*)d_out;

  // aliased f16 workspace regions (bytes):
  char* ws = (char*)d_ws;
  f16* R0 = (f16*)(ws);                 //  8.4MB: X0 (8192x512)  then W2f (2048x2048)
  f16* R1 = (f16*)(ws + 8388608);       //  2.1MB: W1f (2048x512) then W3f (512x2048)
  f16* R2 = (f16*)(ws + 10485760);      // 16.8MB: Mt1 then Mt2   (8x1024x1024)
  f16* R3 = (f16*)(ws + 27262976);      // 33.6MB: Xt1 then bufD  (8192x2048)
  f16* R4 = (f16*)(ws + 60817408);      // 33.6MB: bufB
  f16* R5 = (f16*)(ws + 94371840);      // 33.6MB: Xt2

  // 1. embeddings + LN -> X0 (f16)
  embed_ln_kernel<<<ROWS, 256, 0, stream>>>(x, wemb, pemb, temb, lnw, lnb, R0);
  // 2. W1 -> f16 ; Mt1
  cast_f16_kernel<<<(INTER * HID / 4 + 255) / 256, 256, 0, stream>>>(init_d, R1, INTER * HID);
  mtrans_kernel<<<dim3(32, 32, 8), 256, 0, stream>>>(init_M, R2);
  // 3. gemm1: Xt1 = X0 @ W1^T  (transposed-per-head epilogue)
  gemm256_t_kernel<<<dim3(INTER / 256, ROWS / 256), 256, 0, stream>>>(R0, R1, R3, HID);
  // 4. mut1 -> bufB
  mut256_kernel<<<dim3(1, SEQ / 256, BATCH * NHEAD), 256, 0, stream>>>(R2, R3, init_b, R4);
  // 5. W2 -> f16 (over X0) ; Mt2 (over Mt1)
  cast_f16_kernel<<<(INTER * INTER / 4 + 255) / 256, 256, 0, stream>>>(inter0_d, R0, INTER * INTER);
  mtrans_kernel<<<dim3(32, 32, 8), 256, 0, stream>>>(inter0_M, R2);
  // 6. gemm2: Xt2 = bufB @ W2^T
  gemm256_t_kernel<<<dim3(INTER / 256, ROWS / 256), 256, 0, stream>>>(R4, R0, R5, INTER);
  // 7. mut2 -> bufD (over Xt1)
  mut256_kernel<<<dim3(1, SEQ / 256, BATCH * NHEAD), 256, 0, stream>>>(R2, R5, inter0_b, R3);
  // 8. W3 -> f16 (over W1f)
  cast_f16_kernel<<<(HID * INTER / 4 + 255) / 256, 256, 0, stream>>>(final_d, R1, HID * INTER);
  // 9. gemm3: out = bufD @ W3^T + bias (fp32 out)
  gemm_out_kernel<<<dim3(HID / 128, ROWS / 128), 256, 0, stream>>>(R3, R1, final_b, out, INTER, HID);
}

// Round 8
// 411.522 us; speedup vs baseline: 1.1371x; 1.1371x over previous
//
#include <hip/hip_runtime.h>

typedef _Float16 f16;
typedef _Float16 f16x4 __attribute__((ext_vector_type(4)));
typedef _Float16 f16x8 __attribute__((ext_vector_type(8)));
typedef float    f32x4 __attribute__((ext_vector_type(4)));

#define SEQ   1024
#define HID   512
#define NHEAD 8
#define DH    256
#define INTER 2048
#define BATCH 8
#define ROWS  (BATCH * SEQ)   // 8192

// async global->LDS, 16B per lane. LDS dest is wave-uniform base + lane*16.
__device__ __forceinline__ void g2l16(const void* g, void* l) {
  __builtin_amdgcn_global_load_lds(
      (const __attribute__((address_space(1))) void*)g,
      (__attribute__((address_space(3))) void*)l, 16, 0, 0);
}

// ===========================================================================
// 256x256 core, 4-slot LDS ring, ONE mid-iteration barrier per K-32 subtile.
// (r5 structure — best measured: gemm2 73.5us, MfmaUtil 38-39%.)
// C(256x256) += A(256xK) * B^T(256xK); operands k-fast row-major, ld == K.
// 512 threads = 8 waves (2M x 4N); per-wave output 128x64 = acc[8][4].
// LDS: 4 ring slots x (A 16KiB + B 16KiB) = 128 KiB.
// Iter t: reads0(slot t) ; MFMA0 ; reads1(slot t) ; stage tile t+3 into
// slot (t+3)&3 ; vmcnt(8)+s_barrier ; MFMA1.  Post-barrier MFMA1 is
// independent of iter t+1's reads -> compiler schedules next reads under it.
// Safety is barrier-ordered: slot t is only read BEFORE barrier(t) and only
// overwritten by staging of t+4, issued AFTER barrier(t).  vmcnt(8) = tiles
// t+2,t+3 (8 calls) in flight, tile t+1 landed; tail: vmcnt(4)->vmcnt(0).
// Swizzle (verified, 0-conflict): k-octet q of row r at slot q^((r>>1)&3),
// involution pre-applied on the GLOBAL source address; ds_read matches.
// ===========================================================================
__device__ __forceinline__ void mm_core256(const f16* __restrict__ At,
                                           const f16* __restrict__ Bt,
                                           int K, f32x4 (&acc)[8][4]) {
  __shared__ __align__(16) f16 As[4 * 8192];
  __shared__ __align__(16) f16 Bs[4 * 8192];
  const int tid  = threadIdx.x;
  const int lane = tid & 63, wv = tid >> 6;
  const int wrow = (wv >> 2) * 128, wcol = (wv & 3) * 64;

  // staging: subtile = 256 rows x 4 k-octets = 1024 chunks of 16B; 2 calls.
  // call j covers chunk j*512+tid: r=c>>2, s=c&3, global octet q=s^((r>>1)&3).
  const int c0 = tid, c1 = tid + 512;
  const int r0 = c0 >> 2, s0 = c0 & 3;
  const int r1 = c1 >> 2, s1 = c1 & 3;
  const int g0 = r0 * K + ((s0 ^ ((r0 >> 1) & 3)) << 3);  // pre-swizzled src
  const int g1 = r1 * K + ((s1 ^ ((r1 >> 1) & 3)) << 3);
  const int l0 = wv * 512;          // per-wave LDS base (f16), call 0
  const int l1 = 4096 + wv * 512;   // call 1

  // fragment read offsets within a subtile (swizzled, matches source perm)
  int aoff[8], boff[4];
  const int q = lane >> 4;
  #pragma unroll
  for (int m = 0; m < 8; ++m) {
    int r = wrow + m * 16 + (lane & 15);
    aoff[m] = r * 32 + ((q ^ ((r >> 1) & 3)) << 3);
  }
  #pragma unroll
  for (int n = 0; n < 4; ++n) {
    int r = wcol + n * 16 + (lane & 15);
    boff[n] = r * 32 + ((q ^ ((r >> 1) & 3)) << 3);
  }

  const int nt = K >> 5;   // K-32 subtiles
  // prologue: stage tiles 0,1,2 -> slots 0,1,2 (12 calls, 4 per tile)
  #pragma unroll
  for (int p = 0; p < 3; ++p) {
    const int kb = p << 5, sb = p * 8192;
    g2l16(At + kb + g0, &As[sb + l0]);
    g2l16(At + kb + g1, &As[sb + l1]);
    g2l16(Bt + kb + g0, &Bs[sb + l0]);
    g2l16(Bt + kb + g1, &Bs[sb + l1]);
  }
  asm volatile("s_waitcnt vmcnt(8)" ::: "memory");   // tile 0 landed
  __builtin_amdgcn_s_barrier();

  for (int t = 0; t < nt; ++t) {
    const int cb = (t & 3) * 8192;

    // reads0: B-frags + A-frags (lower half) from slot t
    f16x8 bfr[4], af0[4], af1[4];
    #pragma unroll
    for (int n = 0; n < 4; ++n) bfr[n] = *(const f16x8*)&Bs[cb + boff[n]];
    #pragma unroll
    for (int m = 0; m < 4; ++m) af0[m] = *(const f16x8*)&As[cb + aoff[m]];

    // MFMA cluster 0
    __builtin_amdgcn_s_setprio(1);
    #pragma unroll
    for (int m = 0; m < 4; ++m)
      #pragma unroll
      for (int n = 0; n < 4; ++n)
        acc[m][n] = __builtin_amdgcn_mfma_f32_16x16x32_f16(af0[m], bfr[n],
                                                           acc[m][n], 0, 0, 0);
    __builtin_amdgcn_s_setprio(0);

    // reads1: A-frags (upper half) from slot t — still pre-barrier
    #pragma unroll
    for (int m = 0; m < 4; ++m) af1[m] = *(const f16x8*)&As[cb + aoff[m + 4]];

    // stage tile t+3 into slot (t+3)&3 (disjoint from slots t..t+2)
    if (t + 3 < nt) {
      const int kb = (t + 3) << 5, sb = ((t + 3) & 3) * 8192;
      g2l16(At + kb + g0, &As[sb + l0]);
      g2l16(At + kb + g1, &As[sb + l1]);
      g2l16(Bt + kb + g0, &Bs[sb + l0]);
      g2l16(Bt + kb + g1, &Bs[sb + l1]);
    }

    // single per-subtile sync: tile t+1 guaranteed resident after this
    if (t + 1 < nt) {
      if (t + 3 < nt)      asm volatile("s_waitcnt vmcnt(8)" ::: "memory");
      else if (t + 2 < nt) asm volatile("s_waitcnt vmcnt(4)" ::: "memory");
      else                 asm volatile("s_waitcnt vmcnt(0)" ::: "memory");
      __builtin_amdgcn_s_barrier();
    }

    // MFMA cluster 1 — post-barrier; next iter's reads overlap this
    __builtin_amdgcn_s_setprio(1);
    #pragma unroll
    for (int m = 0; m < 4; ++m)
      #pragma unroll
      for (int n = 0; n < 4; ++n)
        acc[m + 4][n] = __builtin_amdgcn_mfma_f32_16x16x32_f16(af1[m], bfr[n],
                                                               acc[m + 4][n], 0, 0, 0);
    __builtin_amdgcn_s_setprio(0);
  }
}

__device__ __forceinline__ void zero_acc8(f32x4 (&acc)[8][4]) {
  f32x4 z = {0.f, 0.f, 0.f, 0.f};
  #pragma unroll
  for (int i = 0; i < 8; ++i)
    #pragma unroll
    for (int j = 0; j < 4; ++j) acc[i][j] = z;
}

// ---------------------------------------------------------------------------
// 256-tile GEMM writing activation in per-head transposed layout Xt[b,h,d,s].
// A: [8192][K] f16, W: [2048][K] f16. N fixed = 2048 (8 heads x 256).
// Grid is ALWAYS (8, 32). XCD-aware bijective remap: HW round-robins the
// dispatch linear index i across 8 XCDs; map i -> lin=(i&7)*32+(i>>3) so
// each XCD owns a 4-row x 8-col chunk (A-panels L2-resident per XCD).
// ---------------------------------------------------------------------------
__global__ __launch_bounds__(512, 2) void gemm256_t_kernel(
    const f16* __restrict__ A, const f16* __restrict__ W,
    f16* __restrict__ Xt, int K) {
  int i = blockIdx.y * 8 + blockIdx.x;          // HW dispatch linear (gridX=8)
  int lin = (i & 7) * 32 + (i >> 3);            // bijective (256 = 8*32)
  int bx = lin & 7, by = lin >> 3;
  int row0 = by * 256, col0 = bx * 256;
  f32x4 acc[8][4];
  zero_acc8(acc);
  mm_core256(A + (size_t)row0 * K, W + (size_t)col0 * K, K, acc);
  int tid = threadIdx.x, lane = tid & 63, wv = tid >> 6;
  int wrow = (wv >> 2) * 128, wcol = (wv & 3) * 64;
  int cn = lane & 15, rbase = (lane >> 4) * 4;
  int b = row0 >> 10, sbase = row0 & 1023;
  #pragma unroll
  for (int m = 0; m < 8; ++m) {
    int s = sbase + wrow + m * 16 + rbase;           // 4 consecutive s
    #pragma unroll
    for (int n = 0; n < 4; ++n) {
      int col = col0 + wcol + n * 16 + cn;
      int h = col >> 8, d = col & 255;
      f16x4 v = {(f16)acc[m][n][0], (f16)acc[m][n][1],
                 (f16)acc[m][n][2], (f16)acc[m][n][3]};
      *(f16x4*)&Xt[(((size_t)(b * 8 + h) * 256 + d) << 10) + s] = v;
    }
  }
}

// ---------------------------------------------------------------------------
// 256-tile per-head seq mix + bias + square:
// Y[(b,t),(h,d)] = ( sum_s Mt[h,t,s] * Xt[b,h,d,s] + bias[h,d] )^2 (f16 out)
// grid: (1, SEQ/256, B*H). Blocks sharing an Mt panel (same h,t0, varying b)
// have linear ids differing by 32 -> same XCD already; no remap needed.
// ---------------------------------------------------------------------------
__global__ __launch_bounds__(512, 2) void mut256_kernel(
    const f16* __restrict__ Mt, const f16* __restrict__ Xt,
    const float* __restrict__ bias, f16* __restrict__ Y) {
  int b = blockIdx.z >> 3, h = blockIdx.z & 7;
  int t0 = blockIdx.y * 256;
  f32x4 acc[8][4];
  zero_acc8(acc);
  const f16* Ap = Mt + ((size_t)h << 20) + ((size_t)t0 << 10);
  const f16* Bp = Xt + (((size_t)(b * 8 + h)) << 18);
  mm_core256(Ap, Bp, SEQ, acc);
  int tid = threadIdx.x, lane = tid & 63, wv = tid >> 6;
  int wrow = (wv >> 2) * 128, wcol = (wv & 3) * 64;
  int cn = lane & 15, rbase = (lane >> 4) * 4;
  #pragma unroll
  for (int m = 0; m < 8; ++m) {
    int t = t0 + wrow + m * 16 + rbase;
    #pragma unroll
    for (int n = 0; n < 4; ++n) {
      int d = wcol + n * 16 + cn;
      float bb = bias[(h << 8) + d];
      size_t base = (((size_t)(b << 10) + t) << 11) + (h << 8) + d;
      #pragma unroll
      for (int r = 0; r < 4; ++r) {
        float v = acc[m][n][r] + bb;
        Y[base + (size_t)r * INTER] = (f16)(v * v);
      }
    }
  }
}

// ===========================================================================
// 128x128 core (verified): BK=32, global_load_lds staging, double buffer.
// Kept for gemm3 (N=512 -> 256-tile grid would underfill the GPU).
// ===========================================================================
__device__ __forceinline__ void mm_core(const f16* __restrict__ At,
                                        const f16* __restrict__ Bt,
                                        int K, f32x4 (&acc)[4][4]) {
  __shared__ __align__(16) f16 As[2 * 4096];
  __shared__ __align__(16) f16 Bs[2 * 4096];
  const int tid  = threadIdx.x;
  const int lane = tid & 63, wv = tid >> 6;
  const int wm = (wv >> 1) * 64, wn = (wv & 1) * 64;
  const int lrow  = lane & 15;
  const int kfrag = (lane >> 4) * 8;
  const int c0  = wv * 128 + lane;
  const int r0c = c0 >> 2, q0c = c0 & 3;
  const int c1  = c0 + 64;
  const int r1c = c1 >> 2, q1c = c1 & 3;
  const int ga0 = r0c * K + ((q0c ^ ((r0c >> 1) & 3)) << 3);
  const int ga1 = r1c * K + ((q1c ^ ((r1c >> 1) & 3)) << 3);
  f16* lA0 = &As[wv * 1024];
  f16* lA1 = &As[wv * 1024 + 512];
  f16* lB0 = &Bs[wv * 1024];
  f16* lB1 = &Bs[wv * 1024 + 512];
  int aoff[4], boff[4];
  #pragma unroll
  for (int t = 0; t < 4; ++t) {
    int ra = wm + t * 16 + lrow;
    aoff[t] = ra * 32 + (kfrag ^ (((ra >> 1) & 3) << 3));
    int rb = wn + t * 16 + lrow;
    boff[t] = rb * 32 + (kfrag ^ (((rb >> 1) & 3) << 3));
  }
  g2l16(At + ga0, lA0);
  g2l16(At + ga1, lA1);
  g2l16(Bt + ga0, lB0);
  g2l16(Bt + ga1, lB1);
  __syncthreads();
  int cur = 0;
  for (int k0 = 0; k0 < K; k0 += 32) {
    if (k0 + 32 < K) {
      const int nb = (cur ^ 1) * 4096;
      g2l16(At + (k0 + 32) + ga0, lA0 + nb);
      g2l16(At + (k0 + 32) + ga1, lA1 + nb);
      g2l16(Bt + (k0 + 32) + ga0, lB0 + nb);
      g2l16(Bt + (k0 + 32) + ga1, lB1 + nb);
    }
    const int cb = cur * 4096;
    f16x8 af[4], bf[4];
    #pragma unroll
    for (int t = 0; t < 4; ++t) {
      af[t] = *(const f16x8*)&As[cb + aoff[t]];
      bf[t] = *(const f16x8*)&Bs[cb + boff[t]];
    }
    #pragma unroll
    for (int i = 0; i < 4; ++i)
      #pragma unroll
      for (int j = 0; j < 4; ++j)
        acc[i][j] = __builtin_amdgcn_mfma_f32_16x16x32_f16(af[i], bf[j],
                                                           acc[i][j], 0, 0, 0);
    __syncthreads();
    cur ^= 1;
  }
}

__device__ __forceinline__ void zero_acc(f32x4 (&acc)[4][4]) {
  f32x4 z = {0.f, 0.f, 0.f, 0.f};
  #pragma unroll
  for (int i = 0; i < 4; ++i)
    #pragma unroll
    for (int j = 0; j < 4; ++j) acc[i][j] = z;
}

// ---------------------------------------------------------------------------
// final GEMM: out fp32 = A @ W^T + bias.  A: [8192][K] f16, W: [N][K] f16.
// ---------------------------------------------------------------------------
__global__ __launch_bounds__(256) void gemm_out_kernel(
    const f16* __restrict__ A, const f16* __restrict__ W,
    const float* __restrict__ bias, float* __restrict__ out, int K, int N) {
  int row0 = blockIdx.y * 128, col0 = blockIdx.x * 128;
  f32x4 acc[4][4];
  zero_acc(acc);
  mm_core(A + (size_t)row0 * K, W + (size_t)col0 * K, K, acc);
  int tid = threadIdx.x, lane = tid & 63, wv = tid >> 6;
  int wm = (wv >> 1) * 64, wn = (wv & 1) * 64;
  int cn = lane & 15, rbase = (lane >> 4) * 4;
  #pragma unroll
  for (int mt = 0; mt < 4; ++mt) {
    int r0 = row0 + wm + mt * 16 + rbase;
    #pragma unroll
    for (int nt = 0; nt < 4; ++nt) {
      int col = col0 + wn + nt * 16 + cn;
      float bb = bias[col];
      #pragma unroll
      for (int r = 0; r < 4; ++r)
        out[(size_t)(r0 + r) * N + col] = acc[mt][nt][r] + bb;
    }
  }
}

// ---------------------------------------------------------------------------
// embeddings + layernorm -> f16
// ---------------------------------------------------------------------------
__global__ __launch_bounds__(256) void embed_ln_kernel(
    const int* __restrict__ x, const float* __restrict__ wemb,
    const float* __restrict__ pemb, const float* __restrict__ temb,
    const float* __restrict__ lnw, const float* __restrict__ lnb,
    f16* __restrict__ out) {
  int row = blockIdx.x;
  int s = row & (SEQ - 1);
  int tok = x[row];
  const float* we = wemb + (size_t)tok * HID;
  const float* pe = pemb + (size_t)s * HID;
  int c = threadIdx.x;
  float e0 = we[c] + pe[c] + temb[c];
  float e1 = we[c + 256] + pe[c + 256] + temb[c + 256];
  float s1 = e0 + e1, s2 = e0 * e0 + e1 * e1;
  #pragma unroll
  for (int off = 32; off > 0; off >>= 1) {
    s1 += __shfl_down(s1, off, 64);
    s2 += __shfl_down(s2, off, 64);
  }
  __shared__ float r1[4], r2[4];
  int wid = threadIdx.x >> 6, lane = threadIdx.x & 63;
  if (lane == 0) { r1[wid] = s1; r2[wid] = s2; }
  __syncthreads();
  float S1 = r1[0] + r1[1] + r1[2] + r1[3];
  float S2 = r2[0] + r2[1] + r2[2] + r2[3];
  float m = S1 * (1.0f / HID);
  float v = S2 * (1.0f / HID) - m * m;
  float inv = rsqrtf(v + 1e-12f);
  f16* o = out + (size_t)row * HID;
  o[c]       = (f16)((e0 - m) * inv * lnw[c]       + lnb[c]);
  o[c + 256] = (f16)((e1 - m) * inv * lnw[c + 256] + lnb[c + 256]);
}

// ---------------------------------------------------------------------------
// f32 -> f16 cast (n % 4 == 0)
// ---------------------------------------------------------------------------
__global__ __launch_bounds__(256) void cast_f16_kernel(
    const float* __restrict__ in, f16* __restrict__ out, int n) {
  int i = (blockIdx.x * 256 + threadIdx.x) * 4;
  if (i < n) {
    float4 v = *(const float4*)(in + i);
    f16x4 o = {(f16)v.x, (f16)v.y, (f16)v.z, (f16)v.w};
    *(f16x4*)(out + i) = o;
  }
}

// ---------------------------------------------------------------------------
// per-head transpose+cast: Mt[h][t][s] = (f16) M[h][s][t]   (1024x1024 x 8)
// ---------------------------------------------------------------------------
__global__ __launch_bounds__(256) void mtrans_kernel(
    const float* __restrict__ M, f16* __restrict__ Mt) {
  __shared__ float T[32][33];
  int h = blockIdx.z;
  int s0 = blockIdx.y * 32, t0 = blockIdx.x * 32;
  int tx = threadIdx.x & 31, ty = threadIdx.x >> 5;   // ty 0..7
  const float* Mh = M + ((size_t)h << 20);
  #pragma unroll
  for (int i = 0; i < 32; i += 8)
    T[ty + i][tx] = Mh[((size_t)(s0 + ty + i) << 10) + t0 + tx];
  __syncthreads();
  f16* Mth = Mt + ((size_t)h << 20);
  #pragma unroll
  for (int i = 0; i < 32; i += 8)
    Mth[((size_t)(t0 + ty + i) << 10) + s0 + tx] = (f16)T[tx][ty + i];
}

// ---------------------------------------------------------------------------
extern "C" void kernel_launch(void* const* d_in, const int* in_sizes, int n_in,
                              void* d_out, int out_size, void* d_ws, size_t ws_size,
                              hipStream_t stream) {
  const int*   x        = (const int*)d_in[0];
  const float* wemb     = (const float*)d_in[1];
  const float* pemb     = (const float*)d_in[2];
  const float* temb     = (const float*)d_in[3];
  const float* lnw      = (const float*)d_in[4];
  const float* lnb      = (const float*)d_in[5];
  const float* init_d   = (const float*)d_in[6];
  const float* init_b   = (const float*)d_in[7];
  const float* init_M   = (const float*)d_in[8];
  const float* inter0_d = (const float*)d_in[9];
  const float* inter0_b = (const float*)d_in[10];
  const float* inter0_M = (const float*)d_in[11];
  const float* final_d  = (const float*)d_in[12];
  const float* final_b  = (const float*)d_in[13];
  float* out = (float*)d_out;

  // aliased f16 workspace regions (bytes):
  char* ws = (char*)d_ws;
  f16* R0 = (f16*)(ws);                 //  8.4MB: X0 (8192x512)  then W2f (2048x2048)
  f16* R1 = (f16*)(ws + 8388608);       //  2.1MB: W1f (2048x512) then W3f (512x2048)
  f16* R2 = (f16*)(ws + 10485760);      // 16.8MB: Mt1 then Mt2   (8x1024x1024)
  f16* R3 = (f16*)(ws + 27262976);      // 33.6MB: Xt1 then bufD  (8192x2048)
  f16* R4 = (f16*)(ws + 60817408);      // 33.6MB: bufB
  f16* R5 = (f16*)(ws + 94371840);      // 33.6MB: Xt2

  // 1. embeddings + LN -> X0 (f16)
  embed_ln_kernel<<<ROWS, 256, 0, stream>>>(x, wemb, pemb, temb, lnw, lnb, R0);
  // 2. W1 -> f16 ; Mt1
  cast_f16_kernel<<<(INTER * HID / 4 + 255) / 256, 256, 0, stream>>>(init_d, R1, INTER * HID);
  mtrans_kernel<<<dim3(32, 32, 8), 256, 0, stream>>>(init_M, R2);
  // 3. gemm1: Xt1 = X0 @ W1^T  (transposed-per-head epilogue)
  gemm256_t_kernel<<<dim3(INTER / 256, ROWS / 256), 512, 0, stream>>>(R0, R1, R3, HID);
  // 4. mut1 -> bufB
  mut256_kernel<<<dim3(1, SEQ / 256, BATCH * NHEAD), 512, 0, stream>>>(R2, R3, init_b, R4);
  // 5. W2 -> f16 (over X0) ; Mt2 (over Mt1)
  cast_f16_kernel<<<(INTER * INTER / 4 + 255) / 256, 256, 0, stream>>>(inter0_d, R0, INTER * INTER);
  mtrans_kernel<<<dim3(32, 32, 8), 256, 0, stream>>>(inter0_M, R2);
  // 6. gemm2: Xt2 = bufB @ W2^T
  gemm256_t_kernel<<<dim3(INTER / 256, ROWS / 256), 512, 0, stream>>>(R4, R0, R5, INTER);
  // 7. mut2 -> bufD (over Xt1)
  mut256_kernel<<<dim3(1, SEQ / 256, BATCH * NHEAD), 512, 0, stream>>>(R2, R5, inter0_b, R3);
  // 8. W3 -> f16 (over W1f)
  cast_f16_kernel<<<(HID * INTER / 4 + 255) / 256, 256, 0, stream>>>(final_d, R1, HID * INTER);
  // 9. gemm3: out = bufD @ W3^T + bias (fp32 out)
  gemm_out_kernel<<<dim3(HID / 128, ROWS / 128), 256, 0, stream>>>(R3, R1, final_b, out, INTER, HID);
}